// Round 1
// 14961.250 us; speedup vs baseline: 1.9799x; 1.9799x over previous
//
#include <hip/hip_runtime.h>
#include <stdint.h>
#include <stddef.h>

// ---------------- problem constants ----------------
#define T_ 1024
#define B_ 64
#define W_ 512
// layers L = 2

// ---------------- ws layout (bytes) ----------------
#define WS_FLAGS   0        // u32: resets-type evidence bits
#define WS_VOTES   4        // u32: ins bf16 exponent votes
#define WS_MODEF   8        // u32: 0=f32 inputs, 1=bf16 inputs
#define WS_MODER   12       // u32: resets mode 0=i32 1=u8 2=f32 3=bf16
#define WS_ABORT   16       // u32: spin abort valve
#define WS_ROOT0   256      // u32 root barrier counter, layer 0 (own 256B line)
#define WS_ROOT1   512      // u32 root barrier counter, layer 1 (own 256B line)
#define WS_GRP     1024     // u32 [2][8] group counters, stride 256 B (ends 5120)
#define WS_RESETS  8192     // u8[65536] (ends 73728)
#define WS_RING0   131072   // bf16 [8][64][512]  = 524288 B
#define WS_RING1   655360   // bf16 [8][64][512]  = 524288 B
#define WS_WPACK   1179648  // bf16 packed weights: [2][32][96][64][8] = 6291456 B
#define WS_NEEDED  (WS_WPACK + 6291456)

using v8s = __attribute__((ext_vector_type(8))) short;
using v4f = __attribute__((ext_vector_type(4))) float;
typedef unsigned long long u64;

__device__ __forceinline__ uint16_t f2bf(float f) {
  uint32_t x = __float_as_uint(f);
  uint32_t r = (x + 0x7FFFu + ((x >> 16) & 1u)) >> 16;
  return (uint16_t)r;
}
__device__ __forceinline__ float bf2f(uint16_t u) {
  return __uint_as_float(((uint32_t)u) << 16);
}
__device__ __forceinline__ v8s ld_v8s(const uint16_t* p) {
  return *(const v8s*)p;
}
__device__ __forceinline__ v8s cvt8(const float* p) {
  v8s o;
#pragma unroll
  for (int j = 0; j < 8; ++j) o[j] = (short)f2bf(p[j]);
  return o;
}

// ---------------- kernel 1: dtype detection ----------------
__global__ void k_detect(const uint32_t* rst, const uint32_t* insw,
                         uint32_t* flags, uint32_t* votes) {
  int i = blockIdx.x * 256 + threadIdx.x;  // 16384 threads
  uint32_t w = rst[i];
  uint32_t f = 0;
  if (w == 0x3F803F80u || w == 0x00003F80u) f |= 1u;
  if ((w & 0xFEFEFEFEu) == 0u && (w & 0xFFFFFF00u) != 0u) f |= 2u;
  if (w == 0x3F800000u) f |= 4u;
  if (w == 1u) f |= 8u;
  if (f) atomicOr(flags, f);
  if (i < 4096) {
    uint32_t b7 = (insw[i] >> 8) & 0x7Fu;
    if (b7 >= 0x3Au && b7 <= 0x41u) atomicAdd(votes, 1u);
  }
}

// ---------------- kernel 2: init ----------------
__global__ void k_init(const uint8_t* rst_raw, uint8_t* ws8) {
  int tid = blockIdx.x * 256 + threadIdx.x;  // 262144 threads
  uint32_t fl = *(const uint32_t*)(ws8 + WS_FLAGS);
  uint32_t vt = *(const uint32_t*)(ws8 + WS_VOTES);
  int modeF = (vt > 2048u) ? 1 : 0;
  int modeR;
  if (fl & 1u) modeR = 3;
  else if (fl & 2u) modeR = 1;
  else if (fl & 4u) modeR = modeF ? 3 : 2;
  else modeR = 0;
  if (tid == 0) {
    *(uint32_t*)(ws8 + WS_MODEF) = (uint32_t)modeF;
    *(uint32_t*)(ws8 + WS_MODER) = (uint32_t)modeR;
  }
  // zero both rings (1 MB total = 262144 u32 words); flushed to memory at
  // kernel end by the implicit dispatch release, so k_gru's MALL-coherent
  // reads see the zeros.
  ((uint32_t*)(ws8 + WS_RING0))[tid] = 0u;
  if (tid < 65536) {
    bool v;
    if (modeR == 1)      v = rst_raw[tid] != 0;
    else if (modeR == 3) v = ((const uint16_t*)rst_raw)[tid] != 0;
    else                 v = ((const uint32_t*)rst_raw)[tid] != 0u;
    ws8[WS_RESETS + tid] = v ? 1 : 0;
  }
}

// ---------------- kernel 3: weight prepack into B-fragment order ----------------
__global__ void k_prepack(const float* w32i, const uint16_t* w16i,
                          const float* w32h, const uint16_t* w16h, uint8_t* ws8) {
  int tid = blockIdx.x * 256 + threadIdx.x;  // 393216 threads
  int lane = tid & 63;
  int fragrow = (tid >> 6) % 96;
  int lg = tid / (96 * 64);  // 0..63
  int l = lg >> 5, g = lg & 31;
  int modeF = (int)*(const uint32_t*)(ws8 + WS_MODEF);
  int cg, kc;
  if (fragrow < 32)      { cg = 0; kc = fragrow; }
  else if (fragrow < 64) { cg = 1; kc = fragrow - 32; }
  else if (fragrow < 80) { cg = 2; kc = fragrow - 64; }
  else                   { cg = 3; kc = fragrow - 80; }
  int n = lane & 15, quad = lane >> 4;
  uint16_t* dst = (uint16_t*)(ws8 + WS_WPACK) + ((size_t)(lg * 96 + fragrow) * 64 + lane) * 8;
#pragma unroll
  for (int j = 0; j < 8; ++j) {
    int k = kc * 32 + quad * 8 + j;
    int col, kk;
    bool useWi;
    if (cg == 0)      { col = g * 16 + n;        useWi = (k < 512); kk = k & 511; }
    else if (cg == 1) { col = 512 + g * 16 + n;  useWi = (k < 512); kk = k & 511; }
    else if (cg == 2) { col = 1024 + g * 16 + n; useWi = true;      kk = k; }
    else              { col = 1024 + g * 16 + n; useWi = false;     kk = k; }
    size_t si = ((size_t)l * 512 + kk) * 1536 + col;
    uint16_t v;
    if (modeF) v = useWi ? w16i[si] : w16h[si];
    else       v = f2bf(useWi ? w32i[si] : w32h[si]);
    dst[j] = v;
  }
}

// ---------------- spin helper (relaxed agent loads; no fences) ----------------
__device__ __forceinline__ void spin_ge(uint32_t* p, int need, uint32_t* abortf) {
  if (need <= 0) return;
  int polls = 0;
  while ((int)__hip_atomic_load(p, __ATOMIC_RELAXED, __HIP_MEMORY_SCOPE_AGENT) < need) {
    __builtin_amdgcn_s_sleep(1);
    if ((++polls & 255) == 0) {
      if (__hip_atomic_load(abortf, __ATOMIC_RELAXED, __HIP_MEMORY_SCOPE_AGENT)) return;
      if (polls > (1 << 22)) {
        __hip_atomic_store(abortf, 1u, __ATOMIC_RELAXED, __HIP_MEMORY_SCOPE_AGENT);
        return;
      }
    }
  }
}

// ---------------- LDS staging (coherent MALL loads -> swizzled LDS) ----------
// sbuf: 16 rows x 1024 B; row r byte w stored at r*1024 + (w ^ ((r&7)<<4)).
// gsrc: 16 KB contiguous (16 consecutive batch rows of one ring slot).
// Loads are relaxed agent-scope atomics: they bypass the (possibly stale)
// per-XCD L2 and read the coherent point. Issued as 8 independent loads
// before any LDS write so they overlap.
__device__ __forceinline__ void stage16k(uint16_t* __restrict__ sbuf,
                                         const uint8_t* __restrict__ gsrc, int tid) {
  u64 v[8];
#pragma unroll
  for (int c = 0; c < 4; ++c) {
    const u64* gp = (const u64*)(gsrc + tid * 64 + c * 16);
    v[2 * c]     = __hip_atomic_load(gp,     __ATOMIC_RELAXED, __HIP_MEMORY_SCOPE_AGENT);
    v[2 * c + 1] = __hip_atomic_load(gp + 1, __ATOMIC_RELAXED, __HIP_MEMORY_SCOPE_AGENT);
  }
#pragma unroll
  for (int c = 0; c < 4; ++c) {
    int L = tid * 64 + c * 16;
    int row = L >> 10, w = L & 1023;
    uint8_t* d = (uint8_t*)sbuf + row * 1024 + (w ^ ((row & 7) << 4));
    *(u64*)d = v[2 * c];
    *(u64*)(d + 8) = v[2 * c + 1];
  }
}

// MFMA A-fragment read from swizzled stage buffer. row = l16, wb = byte offset
// within the 1024 B row. XOR swizzle makes the 16-lanes-same-quad read pattern
// bank-conflict-free (2-way aliasing only, which is free).
__device__ __forceinline__ v8s ld_frag(const uint16_t* sbuf, int row, int wb) {
  return *(const v8s*)((const uint8_t*)sbuf + row * 1024 + (wb ^ ((row & 7) << 4)));
}

// ---------------- kernel 4: persistent pipelined GRU ----------------
// grid 256 = 2 layers x 32 col-slices x 4 row-tiles. block 256 (4 waves).
// wave 0: r-gate (K=1024), wave 1: z-gate (K=1024), wave 2: inn (K=512, x),
// wave 3: hn (K=512, h) + epilogue owner (holds fp32 h master).
// NO agent fences anywhere in the loop: ring traffic goes through relaxed
// agent-scope atomics (write-through / L2-bypass); ordering comes from the
// vmcnt(0) drain __syncthreads performs per wave + MALL serialization.
__launch_bounds__(256, 1)
__global__ void k_gru(const uint16_t* ins16, const float* ins32,
                      const float* bi32, const uint16_t* bi16,
                      const float* bhn32, const uint16_t* bhn16,
                      float* out32, uint16_t* out16, uint8_t* ws8) {
  const int tid = threadIdx.x;
  const int wave = tid >> 6, lane = tid & 63;
  const int quad = lane >> 4, l16 = lane & 15;
  const int bid = (int)blockIdx.x;
  const int l = bid & 1;
  const int g = (bid >> 1) & 31;
  const int rt = (bid >> 6) & 3;
  const int wgid = rt * 32 + g;   // 0..127 within layer
  const int gid = wgid >> 4;      // 0..7

  uint32_t* rootS = (uint32_t*)(ws8 + (l ? WS_ROOT1 : WS_ROOT0));
  uint32_t* rootO = (uint32_t*)(ws8 + (l ? WS_ROOT0 : WS_ROOT1));
  uint32_t* grp   = (uint32_t*)(ws8 + WS_GRP + (size_t)(l * 8 + gid) * 256);
  uint32_t* abortf = (uint32_t*)(ws8 + WS_ABORT);
  const uint8_t* rst = ws8 + WS_RESETS;
  uint16_t* ring0 = (uint16_t*)(ws8 + WS_RING0);
  uint16_t* ring1 = (uint16_t*)(ws8 + WS_RING1);
  uint16_t* ringS = l ? ring1 : ring0;
  const uint16_t* wsw = (const uint16_t*)(ws8 + WS_WPACK);
  const int modeF = (int)*(volatile const uint32_t*)(ws8 + WS_MODEF);

  // --- load this wave's B fragments into registers (persistent) ---
  const int slice = l * 32 + g;
  const uint16_t* wbase = wsw + (size_t)slice * (96 * 64 * 8);
  const int nB = (wave < 2) ? 32 : 16;
  const int fb = (wave < 2) ? wave * 32 : 64 + (wave - 2) * 16;
  v8s Bv[32];
#pragma unroll
  for (int i = 0; i < 32; ++i)
    if (i < nB) Bv[i] = ld_v8s(wbase + ((size_t)(fb + i) * 64 + lane) * 8);

  // --- per-lane constants ---
  const int rowbase = rt * 16;
  const int bA = rowbase + l16;   // batch row this lane computes A for
  const int cC = g * 16 + l16;    // n-column this lane owns in C/epilogue
  const int wb0 = quad * 16;      // A-fragment byte offset within k-chunk
  float bir, biz, bin_, bh;
  if (modeF) {
    const uint16_t* b16 = bi16 + l * 1536;
    bir = bf2f(b16[cC]); biz = bf2f(b16[512 + cC]); bin_ = bf2f(b16[1024 + cC]);
    bh = bf2f(bhn16[l * 512 + cC]);
  } else {
    const float* b32 = bi32 + l * 1536;
    bir = b32[cC]; biz = b32[512 + cC]; bin_ = b32[1024 + cC];
    bh = bhn32[l * 512 + cC];
  }

  __shared__ uint16_t hbuf[8192];              // h(t-1), 16 rows, swizzled
  __shared__ uint16_t xbuf[8192];              // x(t) for layer 1, swizzled
  __shared__ float eb[3][64][5];               // gate partials (padded stride 5)
  __shared__ __align__(16) uint16_t hstage[16][16];  // epilogue repack block

  float hm[4] = {0.f, 0.f, 0.f, 0.f};
  const int rEnd = l ? (T_ + 1) : T_;
  const v8s vzero = {0, 0, 0, 0, 0, 0, 0, 0};

  for (int r = 0; r < rEnd; ++r) {
    // ---- wait: own layer finished r-1; other layer far enough along ----
    if (tid == 0) {
      spin_ge(rootS, r * 8, abortf);
      spin_ge(rootO, l ? r * 8 : (r - 6) * 8, abortf);
    }
    __syncthreads();  // (1) everyone sees the go signal

    const bool active = l ? (r > 0) : true;
    const int t = l ? (r - 1) : r;

    // ---- stage coherent ring data into LDS (once per wg, shared by waves) --
    if (active) {
      stage16k(hbuf, (const uint8_t*)(ringS + (size_t)((t - 1) & 7) * (B_ * W_)
                                      + (size_t)rowbase * 512), tid);
      if (l)
        stage16k(xbuf, (const uint8_t*)(ring0 + (size_t)(t & 7) * (B_ * W_)
                                        + (size_t)rowbase * 512), tid);
    }
    __syncthreads();  // (2) LDS stage visible

    v4f acc = {0.f, 0.f, 0.f, 0.f};
    if (active) {
      const int rsA = (int)rst[t * 64 + bA];

      if (wave < 2) {
#pragma unroll
        for (int kc = 0; kc < 16; ++kc) {  // x part, K 0..511
          v8s a;
          if (l)          a = ld_frag(xbuf, l16, kc * 64 + wb0);
          else if (modeF) a = ld_v8s(ins16 + ((size_t)t * 64 + bA) * 512 + kc * 32 + quad * 8);
          else            a = cvt8(ins32 + ((size_t)t * 64 + bA) * 512 + kc * 32 + quad * 8);
          acc = __builtin_amdgcn_mfma_f32_16x16x32_bf16(a, Bv[kc], acc, 0, 0, 0);
        }
#pragma unroll
        for (int kc = 0; kc < 16; ++kc) {  // h part, K 512..1023
          v8s a = ld_frag(hbuf, l16, kc * 64 + wb0);
          if (rsA) a = vzero;
          acc = __builtin_amdgcn_mfma_f32_16x16x32_bf16(a, Bv[16 + kc], acc, 0, 0, 0);
        }
      } else if (wave == 2) {               // inn: x only
#pragma unroll
        for (int kc = 0; kc < 16; ++kc) {
          v8s a;
          if (l)          a = ld_frag(xbuf, l16, kc * 64 + wb0);
          else if (modeF) a = ld_v8s(ins16 + ((size_t)t * 64 + bA) * 512 + kc * 32 + quad * 8);
          else            a = cvt8(ins32 + ((size_t)t * 64 + bA) * 512 + kc * 32 + quad * 8);
          acc = __builtin_amdgcn_mfma_f32_16x16x32_bf16(a, Bv[kc], acc, 0, 0, 0);
        }
      } else {                              // hn: h only
#pragma unroll
        for (int kc = 0; kc < 16; ++kc) {
          v8s a = ld_frag(hbuf, l16, kc * 64 + wb0);
          if (rsA) a = vzero;
          acc = __builtin_amdgcn_mfma_f32_16x16x32_bf16(a, Bv[kc], acc, 0, 0, 0);
        }
      }
      if (wave < 3) {
#pragma unroll
        for (int i = 0; i < 4; ++i) eb[wave][lane][i] = acc[i];
      }
    }
    __syncthreads();  // (3) gate partials visible

    if (active && wave == 3) {
#pragma unroll
      for (int i = 0; i < 4; ++i) {
        float ra = eb[0][lane][i], za = eb[1][lane][i], ia = eb[2][lane][i], ha = acc[i];
        float rg = 1.f / (1.f + __expf(-(ra + bir)));
        float zg = 1.f / (1.f + __expf(-(za + biz)));
        float narg = ia + bin_ + rg * (ha + bh);
        float e2 = __expf(-2.f * fabsf(narg));
        float ng = (1.f - e2) / (1.f + e2);
        ng = (narg < 0.f) ? -ng : ng;
        int b = rowbase + quad * 4 + i;
        float hp = rst[t * 64 + b] ? 0.f : hm[i];
        float hv = (1.f - zg) * ng + zg * hp;
        hm[i] = hv;
        hstage[quad * 4 + i][l16] = f2bf(hv);
        if (l) {  // ys output (layer-1 hidden) — plain cached stores
          size_t off = (size_t)2 * B_ * W_ + ((size_t)t * 64 + b) * 512 + cC;
          if (modeF) out16[off] = f2bf(hv); else out32[off] = hv;
        }
        if (t == T_ - 1) {  // final carry
          size_t off = (size_t)l * (B_ * W_) + (size_t)b * 512 + cC;
          if (modeF) out16[off] = f2bf(hv); else out32[off] = hv;
        }
      }
    }
    __syncthreads();  // (4) hstage visible to all of wave 3

    if (active && wave == 3) {
      // repack 16x16 block to row-major 8B chunks: one coherent store/lane
      int sr = lane >> 2, sc4 = lane & 3;
      u64 v = *(const u64*)&hstage[sr][sc4 * 4];
      uint16_t* hout = ringS + (size_t)(t & 7) * (B_ * W_);
      u64* dst = (u64*)((uint8_t*)hout
                        + ((size_t)(rowbase + sr) * 512 + (size_t)g * 16) * 2 + sc4 * 8);
      __hip_atomic_store(dst, v, __ATOMIC_RELAXED, __HIP_MEMORY_SCOPE_AGENT);
    }
    __syncthreads();  // (5) wave-3 drains vmcnt at its barrier arrival:
                      //     h-stores are at the coherence point before arrival

    // ---- arrive: tree barrier (16 -> root), all relaxed ----
    if (tid == 0) {
      uint32_t old = __hip_atomic_fetch_add(grp, 1u, __ATOMIC_RELAXED, __HIP_MEMORY_SCOPE_AGENT);
      if ((old & 15u) == 15u)
        __hip_atomic_fetch_add(rootS, 1u, __ATOMIC_RELAXED, __HIP_MEMORY_SCOPE_AGENT);
    }
  }
}

// ---------------- launcher ----------------
extern "C" void kernel_launch(void* const* d_in, const int* in_sizes, int n_in,
                              void* d_out, int out_size, void* d_ws, size_t ws_size,
                              hipStream_t stream) {
  (void)in_sizes; (void)n_in; (void)out_size;
  if (ws_size < (size_t)WS_NEEDED) return;  // visible failure rather than corruption

  const void* ins = d_in[0];
  const void* rst = d_in[1];
  const void* Wi  = d_in[2];
  const void* bi  = d_in[3];
  const void* Wh  = d_in[4];
  const void* bhn = d_in[5];
  uint8_t* ws8 = (uint8_t*)d_ws;

  hipMemsetAsync(d_ws, 0, 8192, stream);  // flags + counters (now 256B-strided)
  hipLaunchKernelGGL(k_detect, dim3(64), dim3(256), 0, stream,
                     (const uint32_t*)rst, (const uint32_t*)ins,
                     (uint32_t*)(ws8 + WS_FLAGS), (uint32_t*)(ws8 + WS_VOTES));
  hipLaunchKernelGGL(k_init, dim3(1024), dim3(256), 0, stream,
                     (const uint8_t*)rst, ws8);
  hipLaunchKernelGGL(k_prepack, dim3(1536), dim3(256), 0, stream,
                     (const float*)Wi, (const uint16_t*)Wi,
                     (const float*)Wh, (const uint16_t*)Wh, ws8);
  hipLaunchKernelGGL(k_gru, dim3(256), dim3(256), 0, stream,
                     (const uint16_t*)ins, (const float*)ins,
                     (const float*)bi, (const uint16_t*)bi,
                     (const float*)bhn, (const uint16_t*)bhn,
                     (float*)d_out, (uint16_t*)d_out, ws8);
}

// Round 3
// 9963.400 us; speedup vs baseline: 2.9731x; 1.5016x over previous
//
#include <hip/hip_runtime.h>
#include <stdint.h>
#include <stddef.h>

// ---------------- problem constants ----------------
#define T_ 1024
#define B_ 64
#define W_ 512
// layers L = 2

// ---------------- ws layout (bytes) ----------------
#define WS_FLAGS   0        // u32: resets-type evidence bits
#define WS_VOTES   4        // u32: ins bf16 exponent votes
#define WS_MODEF   8        // u32: 0=f32 inputs, 1=bf16 inputs
#define WS_MODER   12       // u32: resets mode 0=i32 1=u8 2=f32 3=bf16
#define WS_ABORT   16       // u32: spin abort valve
#define WS_CTR     256      // u32 domain counters [l*4+rt], stride 256 B (ends 2304)
#define WS_RESETS  8192     // u8[65536] (ends 73728)
#define WS_RING0   131072   // bf16 [8][64][512]  = 524288 B
#define WS_RING1   655360   // bf16 [8][64][512]  = 524288 B
#define WS_WPACK   1179648  // bf16 packed weights: [2][32][96][64][8] = 6291456 B
#define WS_NEEDED  (WS_WPACK + 6291456)

using v8s = __attribute__((ext_vector_type(8))) short;
using v4f = __attribute__((ext_vector_type(4))) float;
typedef unsigned long long u64;

__device__ __forceinline__ uint16_t f2bf(float f) {
  uint32_t x = __float_as_uint(f);
  uint32_t r = (x + 0x7FFFu + ((x >> 16) & 1u)) >> 16;
  return (uint16_t)r;
}
__device__ __forceinline__ float bf2f(uint16_t u) {
  return __uint_as_float(((uint32_t)u) << 16);
}
__device__ __forceinline__ v8s ld_v8s(const uint16_t* p) {
  return *(const v8s*)p;
}
__device__ __forceinline__ v8s cvt8(const float* p) {
  v8s o;
#pragma unroll
  for (int j = 0; j < 8; ++j) o[j] = (short)f2bf(p[j]);
  return o;
}
// coherent 16-B fragment load (bypasses stale per-XCD L2; served at MALL)
__device__ __forceinline__ v8s ldc16(const uint16_t* p) {
  union { u64 q[2]; v8s v; } u;
  const u64* q = (const u64*)p;
  u.q[0] = __hip_atomic_load(q,     __ATOMIC_RELAXED, __HIP_MEMORY_SCOPE_AGENT);
  u.q[1] = __hip_atomic_load(q + 1, __ATOMIC_RELAXED, __HIP_MEMORY_SCOPE_AGENT);
  return u.v;
}

// ---------------- kernel 1: dtype detection ----------------
__global__ void k_detect(const uint32_t* rst, const uint32_t* insw,
                         uint32_t* flags, uint32_t* votes) {
  int i = blockIdx.x * 256 + threadIdx.x;  // 16384 threads
  uint32_t w = rst[i];
  uint32_t f = 0;
  if (w == 0x3F803F80u || w == 0x00003F80u) f |= 1u;
  if ((w & 0xFEFEFEFEu) == 0u && (w & 0xFFFFFF00u) != 0u) f |= 2u;
  if (w == 0x3F800000u) f |= 4u;
  if (w == 1u) f |= 8u;
  if (f) atomicOr(flags, f);
  if (i < 4096) {
    uint32_t b7 = (insw[i] >> 8) & 0x7Fu;
    if (b7 >= 0x3Au && b7 <= 0x41u) atomicAdd(votes, 1u);
  }
}

// ---------------- kernel 2: init ----------------
__global__ void k_init(const uint8_t* rst_raw, uint8_t* ws8) {
  int tid = blockIdx.x * 256 + threadIdx.x;  // 262144 threads
  uint32_t fl = *(const uint32_t*)(ws8 + WS_FLAGS);
  uint32_t vt = *(const uint32_t*)(ws8 + WS_VOTES);
  int modeF = (vt > 2048u) ? 1 : 0;
  int modeR;
  if (fl & 1u) modeR = 3;
  else if (fl & 2u) modeR = 1;
  else if (fl & 4u) modeR = modeF ? 3 : 2;
  else modeR = 0;
  if (tid == 0) {
    *(uint32_t*)(ws8 + WS_MODEF) = (uint32_t)modeF;
    *(uint32_t*)(ws8 + WS_MODER) = (uint32_t)modeR;
  }
  // zero both rings (1 MB total = 262144 u32 words); dispatch-end release
  // flushes them so k_gru's MALL-coherent reads see the zeros.
  ((uint32_t*)(ws8 + WS_RING0))[tid] = 0u;
  if (tid < 65536) {
    bool v;
    if (modeR == 1)      v = rst_raw[tid] != 0;
    else if (modeR == 3) v = ((const uint16_t*)rst_raw)[tid] != 0;
    else                 v = ((const uint32_t*)rst_raw)[tid] != 0u;
    ws8[WS_RESETS + tid] = v ? 1 : 0;
  }
}

// ---------------- kernel 3: weight prepack into B-fragment order ----------------
__global__ void k_prepack(const float* w32i, const uint16_t* w16i,
                          const float* w32h, const uint16_t* w16h, uint8_t* ws8) {
  int tid = blockIdx.x * 256 + threadIdx.x;  // 393216 threads
  int lane = tid & 63;
  int fragrow = (tid >> 6) % 96;
  int lg = tid / (96 * 64);  // 0..63
  int l = lg >> 5, g = lg & 31;
  int modeF = (int)*(const uint32_t*)(ws8 + WS_MODEF);
  int cg, kc;
  if (fragrow < 32)      { cg = 0; kc = fragrow; }
  else if (fragrow < 64) { cg = 1; kc = fragrow - 32; }
  else if (fragrow < 80) { cg = 2; kc = fragrow - 64; }
  else                   { cg = 3; kc = fragrow - 80; }
  int n = lane & 15, quad = lane >> 4;
  uint16_t* dst = (uint16_t*)(ws8 + WS_WPACK) + ((size_t)(lg * 96 + fragrow) * 64 + lane) * 8;
#pragma unroll
  for (int j = 0; j < 8; ++j) {
    int k = kc * 32 + quad * 8 + j;
    int col, kk;
    bool useWi;
    if (cg == 0)      { col = g * 16 + n;        useWi = (k < 512); kk = k & 511; }
    else if (cg == 1) { col = 512 + g * 16 + n;  useWi = (k < 512); kk = k & 511; }
    else if (cg == 2) { col = 1024 + g * 16 + n; useWi = true;      kk = k; }
    else              { col = 1024 + g * 16 + n; useWi = false;     kk = k; }
    size_t si = ((size_t)l * 512 + kk) * 1536 + col;
    uint16_t v;
    if (modeF) v = useWi ? w16i[si] : w16h[si];
    else       v = f2bf(useWi ? w32i[si] : w32h[si]);
    dst[j] = v;
  }
}

// ---------------- spin helper (relaxed agent loads; no fences) ----------------
__device__ __forceinline__ void spin_ge(uint32_t* p, int need, uint32_t* abortf) {
  if (need <= 0) return;
  int polls = 0;
  while ((int)__hip_atomic_load(p, __ATOMIC_RELAXED, __HIP_MEMORY_SCOPE_AGENT) < need) {
    __builtin_amdgcn_s_sleep(1);
    if ((++polls & 255) == 0) {
      if (__hip_atomic_load(abortf, __ATOMIC_RELAXED, __HIP_MEMORY_SCOPE_AGENT)) return;
      if (polls > (1 << 22)) {
        __hip_atomic_store(abortf, 1u, __ATOMIC_RELAXED, __HIP_MEMORY_SCOPE_AGENT);
        return;
      }
    }
  }
}

// ---------------- kernel 4: persistent pipelined GRU ----------------
// grid 256 = 2 layers x 32 col-slices x 4 row-tiles. block 256 (4 waves).
// Sync: per (layer, row-tile) domain of 32 wgs, one u32 counter per domain.
// Arrival (PROVEN r1 pattern): all stores drained by the compiler's
// s_waitcnt vmcnt(0) before the last __syncthreads, then tid 0 does ONE
// relaxed agent fetch_add on the domain counter (RMW executes at the MALL).
// Release: tid 0 spins on own-domain counter (>= 32*r) and other-layer
// same-rt counter, then __syncthreads broadcasts.
// wave 0: r-gate (K=1024), wave 1: z-gate (K=1024), wave 2: inn (K=512, x),
// wave 3: hn (K=512, h) + epilogue owner (holds fp32 h master).
__launch_bounds__(256, 1)
__global__ void k_gru(const uint16_t* ins16, const float* ins32,
                      const float* bi32, const uint16_t* bi16,
                      const float* bhn32, const uint16_t* bhn16,
                      float* out32, uint16_t* out16, uint8_t* ws8) {
  const int tid = threadIdx.x;
  const int wave = tid >> 6, lane = tid & 63;
  const int quad = lane >> 4, l16 = lane & 15;
  const int bid = (int)blockIdx.x;
  const int l = bid & 1;
  const int g = (bid >> 1) & 31;
  const int rt = (bid >> 6) & 3;

  uint32_t* abortf = (uint32_t*)(ws8 + WS_ABORT);
  uint32_t* ctrOwn = (uint32_t*)(ws8 + WS_CTR + (size_t)(l * 4 + rt) * 256);
  uint32_t* ctrOth = (uint32_t*)(ws8 + WS_CTR + (size_t)((1 - l) * 4 + rt) * 256);
  const uint8_t* rst = ws8 + WS_RESETS;
  uint16_t* ring0 = (uint16_t*)(ws8 + WS_RING0);
  uint16_t* ring1 = (uint16_t*)(ws8 + WS_RING1);
  uint16_t* ringS = l ? ring1 : ring0;
  const uint16_t* wsw = (const uint16_t*)(ws8 + WS_WPACK);
  const int modeF = (int)*(volatile const uint32_t*)(ws8 + WS_MODEF);

  // --- load this wave's B fragments into registers (persistent) ---
  const int slice = l * 32 + g;
  const uint16_t* wbase = wsw + (size_t)slice * (96 * 64 * 8);
  const int nB = (wave < 2) ? 32 : 16;
  const int fb = (wave < 2) ? wave * 32 : 64 + (wave - 2) * 16;
  v8s Bv[32];
#pragma unroll
  for (int i = 0; i < 32; ++i)
    if (i < nB) Bv[i] = ld_v8s(wbase + ((size_t)(fb + i) * 64 + lane) * 8);

  // --- per-lane constants ---
  const int rowbase = rt * 16;
  const int bA = rowbase + l16;   // batch row this lane computes A for
  const int cC = g * 16 + l16;    // n-column this lane owns in C/epilogue
  float bir, biz, bin_, bh;
  if (modeF) {
    const uint16_t* b16 = bi16 + l * 1536;
    bir = bf2f(b16[cC]); biz = bf2f(b16[512 + cC]); bin_ = bf2f(b16[1024 + cC]);
    bh = bf2f(bhn16[l * 512 + cC]);
  } else {
    const float* b32 = bi32 + l * 1536;
    bir = b32[cC]; biz = b32[512 + cC]; bin_ = b32[1024 + cC];
    bh = bhn32[l * 512 + cC];
  }

  __shared__ __align__(16) float eb[3][64][4];        // gate partials
  __shared__ __align__(16) uint16_t hstage[16][16];   // wave-3 repack block

  float hm0 = 0.f, hm1 = 0.f, hm2 = 0.f, hm3 = 0.f;
  const int rEnd = l ? (T_ + 1) : T_;
  const v8s vzero = {0, 0, 0, 0, 0, 0, 0, 0};

  for (int r = 0; r < rEnd; ++r) {
    // ---- release: tid 0 spins on domain counters ----
    if (tid == 0) {
      spin_ge(ctrOwn, 32 * r, abortf);                      // own domain done r-1
      spin_ge(ctrOth, 32 * (l ? r : r - 6), abortf);        // x ready / throttle
    }
    __syncthreads();                    // (1) go signal for all waves
    asm volatile("" ::: "memory");      // no load hoisting above the spin

    const bool active = l ? (r > 0) : true;
    const int t = l ? (r - 1) : r;

    v4f a0 = {0.f, 0.f, 0.f, 0.f}, a1 = {0.f, 0.f, 0.f, 0.f};
    if (active) {
      const int rsA = (int)rst[t * 64 + bA];
      const uint16_t* hp = ringS + (size_t)((t - 1) & 7) * (B_ * W_) + bA * 512 + quad * 8;
      const uint16_t* xr = ring0 + (size_t)(t & 7) * (B_ * W_) + bA * 512 + quad * 8;
      const uint16_t* xi16 = ins16 + ((size_t)t * 64 + bA) * 512 + quad * 8;
      const float*    xi32 = ins32 + ((size_t)t * 64 + bA) * 512 + quad * 8;

      if (wave < 2) {
#pragma unroll
        for (int kc = 0; kc < 16; kc += 2) {  // x part, K 0..511
          v8s x0, x1;
          if (l)          { x0 = ldc16(xr + kc * 32);    x1 = ldc16(xr + kc * 32 + 32); }
          else if (modeF) { x0 = ld_v8s(xi16 + kc * 32); x1 = ld_v8s(xi16 + kc * 32 + 32); }
          else            { x0 = cvt8(xi32 + kc * 32);   x1 = cvt8(xi32 + kc * 32 + 32); }
          a0 = __builtin_amdgcn_mfma_f32_16x16x32_bf16(x0, Bv[kc], a0, 0, 0, 0);
          a1 = __builtin_amdgcn_mfma_f32_16x16x32_bf16(x1, Bv[kc + 1], a1, 0, 0, 0);
        }
#pragma unroll
        for (int kc = 0; kc < 16; kc += 2) {  // h part, K 512..1023
          v8s h0 = ldc16(hp + kc * 32);
          v8s h1 = ldc16(hp + kc * 32 + 32);
          if (rsA) { h0 = vzero; h1 = vzero; }
          a0 = __builtin_amdgcn_mfma_f32_16x16x32_bf16(h0, Bv[16 + kc], a0, 0, 0, 0);
          a1 = __builtin_amdgcn_mfma_f32_16x16x32_bf16(h1, Bv[16 + kc + 1], a1, 0, 0, 0);
        }
      } else if (wave == 2) {               // inn: x only
#pragma unroll
        for (int kc = 0; kc < 16; kc += 2) {
          v8s x0, x1;
          if (l)          { x0 = ldc16(xr + kc * 32);    x1 = ldc16(xr + kc * 32 + 32); }
          else if (modeF) { x0 = ld_v8s(xi16 + kc * 32); x1 = ld_v8s(xi16 + kc * 32 + 32); }
          else            { x0 = cvt8(xi32 + kc * 32);   x1 = cvt8(xi32 + kc * 32 + 32); }
          a0 = __builtin_amdgcn_mfma_f32_16x16x32_bf16(x0, Bv[kc], a0, 0, 0, 0);
          a1 = __builtin_amdgcn_mfma_f32_16x16x32_bf16(x1, Bv[kc + 1], a1, 0, 0, 0);
        }
      } else {                              // hn: h only
#pragma unroll
        for (int kc = 0; kc < 16; kc += 2) {
          v8s h0 = ldc16(hp + kc * 32);
          v8s h1 = ldc16(hp + kc * 32 + 32);
          if (rsA) { h0 = vzero; h1 = vzero; }
          a0 = __builtin_amdgcn_mfma_f32_16x16x32_bf16(h0, Bv[kc], a0, 0, 0, 0);
          a1 = __builtin_amdgcn_mfma_f32_16x16x32_bf16(h1, Bv[kc + 1], a1, 0, 0, 0);
        }
      }
      if (wave < 3) {
        v4f s = a0 + a1;
        *(v4f*)&eb[wave][lane][0] = s;
      }
    }
    __syncthreads();                    // (2) gate partials visible

    float hv0 = 0.f, hv1 = 0.f, hv2 = 0.f, hv3 = 0.f;
    if (active && wave == 3) {
      v4f accs = a0 + a1;
      v4f ra4 = *(const v4f*)&eb[0][lane][0];
      v4f za4 = *(const v4f*)&eb[1][lane][0];
      v4f ia4 = *(const v4f*)&eb[2][lane][0];
      float hv4[4];
      float hmv[4] = {hm0, hm1, hm2, hm3};
#pragma unroll
      for (int i = 0; i < 4; ++i) {
        float rg = 1.f / (1.f + __expf(-(ra4[i] + bir)));
        float zg = 1.f / (1.f + __expf(-(za4[i] + biz)));
        float narg = ia4[i] + bin_ + rg * (accs[i] + bh);
        float e2 = __expf(-2.f * fabsf(narg));
        float ng = (1.f - e2) / (1.f + e2);
        ng = (narg < 0.f) ? -ng : ng;
        int b = rowbase + quad * 4 + i;
        float hp_ = rst[t * 64 + b] ? 0.f : hmv[i];
        float hv = (1.f - zg) * ng + zg * hp_;
        hv4[i] = hv;
        hstage[quad * 4 + i][l16] = f2bf(hv);
      }
      hm0 = hv4[0]; hm1 = hv4[1]; hm2 = hv4[2]; hm3 = hv4[3];
      hv0 = hv4[0]; hv1 = hv4[1]; hv2 = hv4[2]; hv3 = hv4[3];
      // explicit drain of hstage writes before cross-lane read-back
      asm volatile("s_waitcnt lgkmcnt(0)" ::: "memory");
      __builtin_amdgcn_sched_barrier(0);
      int sr = lane >> 2, sc4 = lane & 3;
      u64 v = *(const u64*)&hstage[sr][sc4 * 4];
      uint16_t* hout = ringS + (size_t)(t & 7) * (B_ * W_);
      u64* dst = (u64*)((uint8_t*)hout
                        + ((size_t)(rowbase + sr) * 512 + (size_t)g * 16) * 2 + sc4 * 8);
      __hip_atomic_store(dst, v, __ATOMIC_RELAXED, __HIP_MEMORY_SCOPE_AGENT);
      // belt-and-braces: drain coherent h-stores before the arrival barrier
      asm volatile("s_waitcnt vmcnt(0)" ::: "memory");
    }
    __syncthreads();                    // (3) full drain (compiler adds waitcnt)

    // ---- arrive: one relaxed RMW at the MALL per wg ----
    if (tid == 0)
      __hip_atomic_fetch_add(ctrOwn, 1u, __ATOMIC_RELAXED, __HIP_MEMORY_SCOPE_AGENT);

    if (active && wave == 3) {
      // deferred outputs (plain cached stores; drain at next step / kernel end)
      float hv4[4] = {hv0, hv1, hv2, hv3};
#pragma unroll
      for (int i = 0; i < 4; ++i) {
        int b = rowbase + quad * 4 + i;
        if (l) {
          size_t off = (size_t)2 * B_ * W_ + ((size_t)t * 64 + b) * 512 + cC;
          if (modeF) out16[off] = f2bf(hv4[i]); else out32[off] = hv4[i];
        }
        if (t == T_ - 1) {
          size_t off = (size_t)l * (B_ * W_) + (size_t)b * 512 + cC;
          if (modeF) out16[off] = f2bf(hv4[i]); else out32[off] = hv4[i];
        }
      }
    }
  }
}

// ---------------- launcher ----------------
extern "C" void kernel_launch(void* const* d_in, const int* in_sizes, int n_in,
                              void* d_out, int out_size, void* d_ws, size_t ws_size,
                              hipStream_t stream) {
  (void)in_sizes; (void)n_in; (void)out_size;
  if (ws_size < (size_t)WS_NEEDED) return;  // visible failure rather than corruption

  const void* ins = d_in[0];
  const void* rst = d_in[1];
  const void* Wi  = d_in[2];
  const void* bi  = d_in[3];
  const void* Wh  = d_in[4];
  const void* bhn = d_in[5];
  uint8_t* ws8 = (uint8_t*)d_ws;

  hipMemsetAsync(d_ws, 0, 8192, stream);  // modes + abort + domain counters
  hipLaunchKernelGGL(k_detect, dim3(64), dim3(256), 0, stream,
                     (const uint32_t*)rst, (const uint32_t*)ins,
                     (uint32_t*)(ws8 + WS_FLAGS), (uint32_t*)(ws8 + WS_VOTES));
  hipLaunchKernelGGL(k_init, dim3(1024), dim3(256), 0, stream,
                     (const uint8_t*)rst, ws8);
  hipLaunchKernelGGL(k_prepack, dim3(1536), dim3(256), 0, stream,
                     (const float*)Wi, (const uint16_t*)Wi,
                     (const float*)Wh, (const uint16_t*)Wh, ws8);
  hipLaunchKernelGGL(k_gru, dim3(256), dim3(256), 0, stream,
                     (const uint16_t*)ins, (const float*)ins,
                     (const float*)bi, (const uint16_t*)bi,
                     (const float*)bhn, (const uint16_t*)bhn,
                     (float*)d_out, (uint16_t*)d_out, ws8);
}

// Round 4
// 8054.833 us; speedup vs baseline: 3.6776x; 1.2369x over previous
//
#include <hip/hip_runtime.h>
#include <stdint.h>
#include <stddef.h>

// ---------------- problem constants ----------------
#define T_ 1024
#define B_ 64
#define W_ 512
// layers L = 2

// ---------------- ws layout (bytes) ----------------
#define WS_FLAGS   0        // u32: resets-type evidence bits
#define WS_VOTES   4        // u32: ins bf16 exponent votes
#define WS_MODEF   8        // u32: 0=f32 inputs, 1=bf16 inputs
#define WS_MODER   12       // u32: resets mode 0=i32 1=u8 2=f32 3=bf16
#define WS_ABORT   16       // u32: spin abort valve
#define WS_CTR     256      // u32 domain counters [l*4+rt], stride 256 B (ends 2304)
#define WS_RESETS  8192     // u8[65536] (ends 73728)
#define WS_RING0   131072   // bf16 [8][64][512]  = 524288 B
#define WS_RING1   655360   // bf16 [8][64][512]  = 524288 B
#define WS_WPACK   1179648  // bf16 packed weights: [2][32][96][64][8] = 6291456 B
#define WS_NEEDED  (WS_WPACK + 6291456)

using v8s = __attribute__((ext_vector_type(8))) short;
using v4f = __attribute__((ext_vector_type(4))) float;
typedef unsigned long long u64;

__device__ __forceinline__ uint16_t f2bf(float f) {
  uint32_t x = __float_as_uint(f);
  uint32_t r = (x + 0x7FFFu + ((x >> 16) & 1u)) >> 16;
  return (uint16_t)r;
}
__device__ __forceinline__ float bf2f(uint16_t u) {
  return __uint_as_float(((uint32_t)u) << 16);
}
__device__ __forceinline__ v8s ld_v8s(const uint16_t* p) {
  return *(const v8s*)p;
}
// coherent 16-B load (bypasses stale per-XCD L2; served at MALL)
__device__ __forceinline__ v8s ldc16(const uint16_t* p) {
  union { u64 q[2]; v8s v; } u;
  const u64* q = (const u64*)p;
  u.q[0] = __hip_atomic_load(q,     __ATOMIC_RELAXED, __HIP_MEMORY_SCOPE_AGENT);
  u.q[1] = __hip_atomic_load(q + 1, __ATOMIC_RELAXED, __HIP_MEMORY_SCOPE_AGENT);
  return u.v;
}

// ---------------- kernel 1: dtype detection ----------------
__global__ void k_detect(const uint32_t* rst, const uint32_t* insw,
                         uint32_t* flags, uint32_t* votes) {
  int i = blockIdx.x * 256 + threadIdx.x;  // 16384 threads
  uint32_t w = rst[i];
  uint32_t f = 0;
  if (w == 0x3F803F80u || w == 0x00003F80u) f |= 1u;
  if ((w & 0xFEFEFEFEu) == 0u && (w & 0xFFFFFF00u) != 0u) f |= 2u;
  if (w == 0x3F800000u) f |= 4u;
  if (w == 1u) f |= 8u;
  if (f) atomicOr(flags, f);
  if (i < 4096) {
    uint32_t b7 = (insw[i] >> 8) & 0x7Fu;
    if (b7 >= 0x3Au && b7 <= 0x41u) atomicAdd(votes, 1u);
  }
}

// ---------------- kernel 2: init ----------------
__global__ void k_init(const uint8_t* rst_raw, uint8_t* ws8) {
  int tid = blockIdx.x * 256 + threadIdx.x;  // 262144 threads
  uint32_t fl = *(const uint32_t*)(ws8 + WS_FLAGS);
  uint32_t vt = *(const uint32_t*)(ws8 + WS_VOTES);
  int modeF = (vt > 2048u) ? 1 : 0;
  int modeR;
  if (fl & 1u) modeR = 3;
  else if (fl & 2u) modeR = 1;
  else if (fl & 4u) modeR = modeF ? 3 : 2;
  else modeR = 0;
  if (tid == 0) {
    *(uint32_t*)(ws8 + WS_MODEF) = (uint32_t)modeF;
    *(uint32_t*)(ws8 + WS_MODER) = (uint32_t)modeR;
  }
  // zero both rings (1 MB total = 262144 u32 words); dispatch-end release
  // flushes them so k_gru's MALL-coherent reads see the zeros.
  ((uint32_t*)(ws8 + WS_RING0))[tid] = 0u;
  if (tid < 65536) {
    bool v;
    if (modeR == 1)      v = rst_raw[tid] != 0;
    else if (modeR == 3) v = ((const uint16_t*)rst_raw)[tid] != 0;
    else                 v = ((const uint32_t*)rst_raw)[tid] != 0u;
    ws8[WS_RESETS + tid] = v ? 1 : 0;
  }
}

// ---------------- kernel 3: weight prepack into B-fragment order ----------------
__global__ void k_prepack(const float* w32i, const uint16_t* w16i,
                          const float* w32h, const uint16_t* w16h, uint8_t* ws8) {
  int tid = blockIdx.x * 256 + threadIdx.x;  // 393216 threads
  int lane = tid & 63;
  int fragrow = (tid >> 6) % 96;
  int lg = tid / (96 * 64);  // 0..63
  int l = lg >> 5, g = lg & 31;
  int modeF = (int)*(const uint32_t*)(ws8 + WS_MODEF);
  int cg, kc;
  if (fragrow < 32)      { cg = 0; kc = fragrow; }
  else if (fragrow < 64) { cg = 1; kc = fragrow - 32; }
  else if (fragrow < 80) { cg = 2; kc = fragrow - 64; }
  else                   { cg = 3; kc = fragrow - 80; }
  int n = lane & 15, quad = lane >> 4;
  uint16_t* dst = (uint16_t*)(ws8 + WS_WPACK) + ((size_t)(lg * 96 + fragrow) * 64 + lane) * 8;
#pragma unroll
  for (int j = 0; j < 8; ++j) {
    int k = kc * 32 + quad * 8 + j;
    int col, kk;
    bool useWi;
    if (cg == 0)      { col = g * 16 + n;        useWi = (k < 512); kk = k & 511; }
    else if (cg == 1) { col = 512 + g * 16 + n;  useWi = (k < 512); kk = k & 511; }
    else if (cg == 2) { col = 1024 + g * 16 + n; useWi = true;      kk = k; }
    else              { col = 1024 + g * 16 + n; useWi = false;     kk = k; }
    size_t si = ((size_t)l * 512 + kk) * 1536 + col;
    uint16_t v;
    if (modeF) v = useWi ? w16i[si] : w16h[si];
    else       v = f2bf(useWi ? w32i[si] : w32h[si]);
    dst[j] = v;
  }
}

// ---------------- spin helper (relaxed agent loads; no fences) ----------------
__device__ __forceinline__ void spin_ge(uint32_t* p, int need, uint32_t* abortf) {
  if (need <= 0) return;
  int polls = 0;
  while ((int)__hip_atomic_load(p, __ATOMIC_RELAXED, __HIP_MEMORY_SCOPE_AGENT) < need) {
    __builtin_amdgcn_s_sleep(1);
    if ((++polls & 255) == 0) {
      if (__hip_atomic_load(abortf, __ATOMIC_RELAXED, __HIP_MEMORY_SCOPE_AGENT)) return;
      if (polls > (1 << 22)) {
        __hip_atomic_store(abortf, 1u, __ATOMIC_RELAXED, __HIP_MEMORY_SCOPE_AGENT);
        return;
      }
    }
  }
}

// ---------------- LDS tile layout (derived conflict-free) ------------------
// Tile = 16 rows x 512 bf16 (16 KB) stored as 1024 16-B chunks.
// chunk(f,row) = f*16 + (row ^ (f & 15)), f = kc*4 + quad (0..63), row 0..15.
// Writes (256 thr, lane-consecutive chunks): each bank hit exactly at the
// b128 floor (8x/bank/wave).  Reads (per-kc ds_read_b128, f fixed per quad):
// 16 lanes per 256-B block hit each bank exactly 2x = floor.  Conflict-free.
__device__ __forceinline__ void st_tile(uint16_t* sb, int f, int row, v8s v) {
  *(v8s*)((uint8_t*)sb + (((f << 4) + (row ^ (f & 15))) << 4)) = v;
}
__device__ __forceinline__ v8s ld_tile(const uint16_t* sb, int f, int row) {
  return *(const v8s*)((const uint8_t*)sb + (((f << 4) + (row ^ (f & 15))) << 4));
}

// stage h tile: coherent ring reads, reset-zeroed rows
__device__ __forceinline__ void stage_hT(uint16_t* sb, const uint16_t* g,
                                         const uint8_t* rrow, int tid) {
  const v8s vz = {0, 0, 0, 0, 0, 0, 0, 0};
#pragma unroll
  for (int i = 0; i < 4; ++i) {
    int c = tid + 256 * i;
    int row = c >> 6, f = c & 63;
    v8s v = ldc16(g + (size_t)c * 8);
    if (rrow[row]) v = vz;
    st_tile(sb, f, row, v);
  }
}
// stage bf16 x tile (no reset): coherent (ring) or cached (ins) source
__device__ __forceinline__ void stage_xbf(uint16_t* sb, const uint16_t* g,
                                          int tid, bool coh) {
#pragma unroll
  for (int i = 0; i < 4; ++i) {
    int c = tid + 256 * i;
    int row = c >> 6, f = c & 63;
    v8s v = coh ? ldc16(g + (size_t)c * 8) : ld_v8s(g + (size_t)c * 8);
    st_tile(sb, f, row, v);
  }
}
// stage f32 x tile: cached loads + one-pass bf16 convert
__device__ __forceinline__ void stage_x32(uint16_t* sb, const float* g, int tid) {
#pragma unroll
  for (int i = 0; i < 8; ++i) {
    int cf = tid + 256 * i;           // 16-B f32 chunk (4 floats)
    int row = cf >> 7, w8 = cf & 127; // 8-B bf16 chunk within row
    int f = w8 >> 1, half = w8 & 1;
    v4f x = *(const v4f*)(g + (size_t)cf * 4);
    u64 v = (u64)f2bf(x[0]) | ((u64)f2bf(x[1]) << 16)
          | ((u64)f2bf(x[2]) << 32) | ((u64)f2bf(x[3]) << 48);
    *(u64*)((uint8_t*)sb + (((f << 4) + (row ^ (f & 15))) << 4) + half * 8) = v;
  }
}

// ---------------- kernel 4: persistent pipelined GRU ----------------
// grid 256 = 2 layers x 32 col-slices x 4 row-tiles. block 256 (4 waves).
// Sync skeleton IDENTICAL to the proven r3 pattern (spin on domain counter,
// barrier-broadcast, vmcnt-drained relaxed fetch_add arrival at the MALL).
// New: ring tiles staged ONCE per wg into LDS (conflict-free layout) so the
// MALL serves 32 instead of 96 requests per line per domain per step; x for
// layer 0 staged+converted once; reset-zeroing applied at stage time; the
// epilogue/publish/RMW tail runs on wave 3 only, off the barrier path.
// wave 0: r-gate (K=1024), wave 1: z-gate (K=1024), wave 2: inn (K=512, x),
// wave 3: hn (K=512, h) + epilogue owner (holds fp32 h master).
__launch_bounds__(256, 1)
__global__ void k_gru(const uint16_t* ins16, const float* ins32,
                      const float* bi32, const uint16_t* bi16,
                      const float* bhn32, const uint16_t* bhn16,
                      float* out32, uint16_t* out16, uint8_t* ws8) {
  const int tid = threadIdx.x;
  const int wave = tid >> 6, lane = tid & 63;
  const int quad = lane >> 4, l16 = lane & 15;
  const int bid = (int)blockIdx.x;
  const int l = bid & 1;
  const int g = (bid >> 1) & 31;
  const int rt = (bid >> 6) & 3;

  uint32_t* abortf = (uint32_t*)(ws8 + WS_ABORT);
  uint32_t* ctrOwn = (uint32_t*)(ws8 + WS_CTR + (size_t)(l * 4 + rt) * 256);
  uint32_t* ctrOth = (uint32_t*)(ws8 + WS_CTR + (size_t)((1 - l) * 4 + rt) * 256);
  const uint8_t* rst = ws8 + WS_RESETS;
  uint16_t* ring0 = (uint16_t*)(ws8 + WS_RING0);
  uint16_t* ring1 = (uint16_t*)(ws8 + WS_RING1);
  uint16_t* ringS = l ? ring1 : ring0;
  const uint16_t* wsw = (const uint16_t*)(ws8 + WS_WPACK);
  const int modeF = (int)*(volatile const uint32_t*)(ws8 + WS_MODEF);

  // --- load this wave's B fragments into registers (persistent) ---
  const int slice = l * 32 + g;
  const uint16_t* wbase = wsw + (size_t)slice * (96 * 64 * 8);
  const int nB = (wave < 2) ? 32 : 16;
  const int fb = (wave < 2) ? wave * 32 : 64 + (wave - 2) * 16;
  v8s Bv[32];
#pragma unroll
  for (int i = 0; i < 32; ++i)
    if (i < nB) Bv[i] = ld_v8s(wbase + ((size_t)(fb + i) * 64 + lane) * 8);

  // --- per-lane constants ---
  const int rowbase = rt * 16;
  const int cC = g * 16 + l16;    // n-column this lane owns in C/epilogue
  float bir, biz, bin_, bh;
  if (modeF) {
    const uint16_t* b16 = bi16 + l * 1536;
    bir = bf2f(b16[cC]); biz = bf2f(b16[512 + cC]); bin_ = bf2f(b16[1024 + cC]);
    bh = bf2f(bhn16[l * 512 + cC]);
  } else {
    const float* b32 = bi32 + l * 1536;
    bir = b32[cC]; biz = b32[512 + cC]; bin_ = b32[1024 + cC];
    bh = bhn32[l * 512 + cC];
  }

  __shared__ __align__(16) uint16_t hT[8192];         // h(t-1) tile, 16 KB
  __shared__ __align__(16) uint16_t xT[8192];         // x(t) tile, 16 KB
  __shared__ __align__(16) float eb[3][64][4];        // gate partials
  __shared__ __align__(16) uint16_t hstage[16][16];   // wave-3 repack block

  float hm0 = 0.f, hm1 = 0.f, hm2 = 0.f, hm3 = 0.f;
  const int rEnd = l ? (T_ + 1) : T_;

  for (int r = 0; r < rEnd; ++r) {
    // ---- release: tid 0 spins on domain counters (proven r3 edge) ----
    if (tid == 0) {
      spin_ge(ctrOwn, 32 * r, abortf);                      // own domain done r-1
      spin_ge(ctrOth, 32 * (l ? r : r - 6), abortf);        // x ready / throttle
    }
    __syncthreads();                    // (A) go signal for all waves
    asm volatile("" ::: "memory");      // no load hoisting above the spin

    const bool active = l ? (r > 0) : true;
    const int t = l ? (r - 1) : r;

    // ---- cooperative one-shot LDS staging (cuts MALL fan-in 3x) ----
    if (active) {
      stage_hT(hT, ringS + (size_t)((t - 1) & 7) * (B_ * W_) + (size_t)rowbase * 512,
               rst + t * 64 + rowbase, tid);
      if (l)          stage_xbf(xT, ring0 + (size_t)(t & 7) * (B_ * W_) + (size_t)rowbase * 512, tid, true);
      else if (modeF) stage_xbf(xT, ins16 + ((size_t)t * 64 + rowbase) * 512, tid, false);
      else            stage_x32(xT, ins32 + ((size_t)t * 64 + rowbase) * 512, tid);
    }
    __syncthreads();                    // (B) stage visible

    v4f a0 = {0.f, 0.f, 0.f, 0.f}, a1 = {0.f, 0.f, 0.f, 0.f};
    if (active) {
      if (wave < 2) {
#pragma unroll
        for (int kc = 0; kc < 16; kc += 2) {  // x part, K 0..511
          v8s x0 = ld_tile(xT, kc * 4 + quad, l16);
          v8s x1 = ld_tile(xT, (kc + 1) * 4 + quad, l16);
          a0 = __builtin_amdgcn_mfma_f32_16x16x32_bf16(x0, Bv[kc], a0, 0, 0, 0);
          a1 = __builtin_amdgcn_mfma_f32_16x16x32_bf16(x1, Bv[kc + 1], a1, 0, 0, 0);
        }
#pragma unroll
        for (int kc = 0; kc < 16; kc += 2) {  // h part, K 512..1023
          v8s h0 = ld_tile(hT, kc * 4 + quad, l16);
          v8s h1 = ld_tile(hT, (kc + 1) * 4 + quad, l16);
          a0 = __builtin_amdgcn_mfma_f32_16x16x32_bf16(h0, Bv[16 + kc], a0, 0, 0, 0);
          a1 = __builtin_amdgcn_mfma_f32_16x16x32_bf16(h1, Bv[16 + kc + 1], a1, 0, 0, 0);
        }
      } else if (wave == 2) {               // inn: x only
#pragma unroll
        for (int kc = 0; kc < 16; kc += 2) {
          v8s x0 = ld_tile(xT, kc * 4 + quad, l16);
          v8s x1 = ld_tile(xT, (kc + 1) * 4 + quad, l16);
          a0 = __builtin_amdgcn_mfma_f32_16x16x32_bf16(x0, Bv[kc], a0, 0, 0, 0);
          a1 = __builtin_amdgcn_mfma_f32_16x16x32_bf16(x1, Bv[kc + 1], a1, 0, 0, 0);
        }
      } else {                              // hn: h only
#pragma unroll
        for (int kc = 0; kc < 16; kc += 2) {
          v8s h0 = ld_tile(hT, kc * 4 + quad, l16);
          v8s h1 = ld_tile(hT, (kc + 1) * 4 + quad, l16);
          a0 = __builtin_amdgcn_mfma_f32_16x16x32_bf16(h0, Bv[kc], a0, 0, 0, 0);
          a1 = __builtin_amdgcn_mfma_f32_16x16x32_bf16(h1, Bv[kc + 1], a1, 0, 0, 0);
        }
      }
      if (wave < 3) {
        v4f s = a0 + a1;
        *(v4f*)&eb[wave][lane][0] = s;
      }
    }
    __syncthreads();                    // (C) gate partials visible

    // ---- wave-3 tail: epilogue, publish, drain, arrive (off barrier path;
    //      waves 0-2 proceed straight to the next step's spin) ----
    if (wave == 3) {
      float hv0 = 0.f, hv1 = 0.f, hv2 = 0.f, hv3 = 0.f;
      if (active) {
        v4f accs = a0 + a1;
        v4f ra4 = *(const v4f*)&eb[0][lane][0];
        v4f za4 = *(const v4f*)&eb[1][lane][0];
        v4f ia4 = *(const v4f*)&eb[2][lane][0];
        float hv4[4];
        float hmv[4] = {hm0, hm1, hm2, hm3};
#pragma unroll
        for (int i = 0; i < 4; ++i) {
          float rg = 1.f / (1.f + __expf(-(ra4[i] + bir)));
          float zg = 1.f / (1.f + __expf(-(za4[i] + biz)));
          float narg = ia4[i] + bin_ + rg * (accs[i] + bh);
          float e2 = __expf(-2.f * fabsf(narg));
          float ng = (1.f - e2) / (1.f + e2);
          ng = (narg < 0.f) ? -ng : ng;
          int b = rowbase + quad * 4 + i;
          float hp_ = rst[t * 64 + b] ? 0.f : hmv[i];
          float hv = (1.f - zg) * ng + zg * hp_;
          hv4[i] = hv;
          hstage[quad * 4 + i][l16] = f2bf(hv);
        }
        hm0 = hv4[0]; hm1 = hv4[1]; hm2 = hv4[2]; hm3 = hv4[3];
        hv0 = hv4[0]; hv1 = hv4[1]; hv2 = hv4[2]; hv3 = hv4[3];
        // explicit drain of hstage writes before cross-lane read-back
        asm volatile("s_waitcnt lgkmcnt(0)" ::: "memory");
        __builtin_amdgcn_sched_barrier(0);
        int sr = lane >> 2, sc4 = lane & 3;
        u64 v = *(const u64*)&hstage[sr][sc4 * 4];
        uint16_t* hout = ringS + (size_t)(t & 7) * (B_ * W_);
        u64* dst = (u64*)((uint8_t*)hout
                          + ((size_t)(rowbase + sr) * 512 + (size_t)g * 16) * 2 + sc4 * 8);
        __hip_atomic_store(dst, v, __ATOMIC_RELAXED, __HIP_MEMORY_SCOPE_AGENT);
        // drain coherent h-stores before signalling arrival
        asm volatile("s_waitcnt vmcnt(0)" ::: "memory");
      }
      // ---- arrive: one relaxed RMW at the MALL per wg (proven r3 edge) ----
      if (lane == 0)
        __hip_atomic_fetch_add(ctrOwn, 1u, __ATOMIC_RELAXED, __HIP_MEMORY_SCOPE_AGENT);

      if (active) {
        // deferred outputs (plain cached stores; off the signal path)
        float hv4[4] = {hv0, hv1, hv2, hv3};
#pragma unroll
        for (int i = 0; i < 4; ++i) {
          int b = rowbase + quad * 4 + i;
          if (l) {
            size_t off = (size_t)2 * B_ * W_ + ((size_t)t * 64 + b) * 512 + cC;
            if (modeF) out16[off] = f2bf(hv4[i]); else out32[off] = hv4[i];
          }
          if (t == T_ - 1) {
            size_t off = (size_t)l * (B_ * W_) + (size_t)b * 512 + cC;
            if (modeF) out16[off] = f2bf(hv4[i]); else out32[off] = hv4[i];
          }
        }
      }
    }
  }
}

// ---------------- launcher ----------------
extern "C" void kernel_launch(void* const* d_in, const int* in_sizes, int n_in,
                              void* d_out, int out_size, void* d_ws, size_t ws_size,
                              hipStream_t stream) {
  (void)in_sizes; (void)n_in; (void)out_size;
  if (ws_size < (size_t)WS_NEEDED) return;  // visible failure rather than corruption

  const void* ins = d_in[0];
  const void* rst = d_in[1];
  const void* Wi  = d_in[2];
  const void* bi  = d_in[3];
  const void* Wh  = d_in[4];
  const void* bhn = d_in[5];
  uint8_t* ws8 = (uint8_t*)d_ws;

  hipMemsetAsync(d_ws, 0, 8192, stream);  // modes + abort + domain counters
  hipLaunchKernelGGL(k_detect, dim3(64), dim3(256), 0, stream,
                     (const uint32_t*)rst, (const uint32_t*)ins,
                     (uint32_t*)(ws8 + WS_FLAGS), (uint32_t*)(ws8 + WS_VOTES));
  hipLaunchKernelGGL(k_init, dim3(1024), dim3(256), 0, stream,
                     (const uint8_t*)rst, ws8);
  hipLaunchKernelGGL(k_prepack, dim3(1536), dim3(256), 0, stream,
                     (const float*)Wi, (const uint16_t*)Wi,
                     (const float*)Wh, (const uint16_t*)Wh, ws8);
  hipLaunchKernelGGL(k_gru, dim3(256), dim3(256), 0, stream,
                     (const uint16_t*)ins, (const float*)ins,
                     (const float*)bi, (const uint16_t*)bi,
                     (const float*)bhn, (const uint16_t*)bhn,
                     (float*)d_out, (uint16_t*)d_out, ws8);
}

// Round 6
// 5500.924 us; speedup vs baseline: 5.3850x; 1.4643x over previous
//
#include <hip/hip_runtime.h>
#include <stdint.h>
#include <stddef.h>

// ---------------- problem constants ----------------
#define T_ 1024
#define B_ 64
#define W_ 512
// layers L = 2

// ---------------- ws layout (bytes) ----------------
#define WS_FLAGS   0        // u32: resets-type evidence bits
#define WS_VOTES   4        // u32: ins bf16 exponent votes
#define WS_MODEF   8        // u32: 0=f32 inputs, 1=bf16 inputs
#define WS_MODER   12       // u32: resets mode 0=i32 1=u8 2=f32 3=bf16
#define WS_ABORT   16       // u32: spin abort valve
#define WS_CTR     256      // u32 domain counters [l*4+rt], stride 256 B (ends 2304)
#define WS_RESETS  8192     // u8[65536] (ends 73728)
#define WS_RING0   131072   // bf16 [8][64][512]  = 524288 B
#define WS_RING1   655360   // bf16 [8][64][512]  = 524288 B
#define WS_WPACK   1179648  // bf16 packed weights: [2][32][96][64][8] = 6291456 B
#define WS_NEEDED  (WS_WPACK + 6291456)

using v8s = __attribute__((ext_vector_type(8))) short;
using v4f = __attribute__((ext_vector_type(4))) float;
typedef unsigned long long u64;

__device__ __forceinline__ uint16_t f2bf(float f) {
  uint32_t x = __float_as_uint(f);
  uint32_t r = (x + 0x7FFFu + ((x >> 16) & 1u)) >> 16;
  return (uint16_t)r;
}
__device__ __forceinline__ float bf2f(uint16_t u) {
  return __uint_as_float(((uint32_t)u) << 16);
}
__device__ __forceinline__ v8s ld_v8s(const uint16_t* p) {
  return *(const v8s*)p;
}
// coherent 16-B load (bypasses L1+L2; served at MALL) — PROVEN r1/r3/r4 edge
__device__ __forceinline__ v8s ldc16(const uint16_t* p) {
  union { u64 q[2]; v8s v; } u;
  const u64* q = (const u64*)p;
  u.q[0] = __hip_atomic_load(q,     __ATOMIC_RELAXED, __HIP_MEMORY_SCOPE_AGENT);
  u.q[1] = __hip_atomic_load(q + 1, __ATOMIC_RELAXED, __HIP_MEMORY_SCOPE_AGENT);
  return u.v;
}
__device__ __forceinline__ uint32_t ld_u32_agent(const uint32_t* p) {
  return __hip_atomic_load(p, __ATOMIC_RELAXED, __HIP_MEMORY_SCOPE_AGENT);
}
__device__ __forceinline__ void st_u64_agent(u64* p, u64 v) {
  __hip_atomic_store(p, v, __ATOMIC_RELAXED, __HIP_MEMORY_SCOPE_AGENT);
}

// ---------------- kernel 1: dtype detection ----------------
__global__ void k_detect(const uint32_t* rst, const uint32_t* insw,
                         uint32_t* flags, uint32_t* votes) {
  int i = blockIdx.x * 256 + threadIdx.x;  // 16384 threads
  uint32_t w = rst[i];
  uint32_t f = 0;
  if (w == 0x3F803F80u || w == 0x00003F80u) f |= 1u;
  if ((w & 0xFEFEFEFEu) == 0u && (w & 0xFFFFFF00u) != 0u) f |= 2u;
  if (w == 0x3F800000u) f |= 4u;
  if (w == 1u) f |= 8u;
  if (f) atomicOr(flags, f);
  if (i < 4096) {
    uint32_t b7 = (insw[i] >> 8) & 0x7Fu;
    if (b7 >= 0x3Au && b7 <= 0x41u) atomicAdd(votes, 1u);
  }
}

// ---------------- kernel 2: init ----------------
__global__ void k_init(const uint8_t* rst_raw, uint8_t* ws8) {
  int tid = blockIdx.x * 256 + threadIdx.x;  // 262144 threads
  uint32_t fl = *(const uint32_t*)(ws8 + WS_FLAGS);
  uint32_t vt = *(const uint32_t*)(ws8 + WS_VOTES);
  int modeF = (vt > 2048u) ? 1 : 0;
  int modeR;
  if (fl & 1u) modeR = 3;
  else if (fl & 2u) modeR = 1;
  else if (fl & 4u) modeR = modeF ? 3 : 2;
  else modeR = 0;
  if (tid == 0) {
    *(uint32_t*)(ws8 + WS_MODEF) = (uint32_t)modeF;
    *(uint32_t*)(ws8 + WS_MODER) = (uint32_t)modeR;
  }
  // zero both h rings (1 MB = 262144 u32); dispatch-end release flushes so
  // k_gru's MALL-coherent reads see the zeros.
  ((uint32_t*)(ws8 + WS_RING0))[tid] = 0u;
  if (tid < 65536) {
    bool v;
    if (modeR == 1)      v = rst_raw[tid] != 0;
    else if (modeR == 3) v = ((const uint16_t*)rst_raw)[tid] != 0;
    else                 v = ((const uint32_t*)rst_raw)[tid] != 0u;
    ws8[WS_RESETS + tid] = v ? 1 : 0;
  }
}

// ---------------- kernel 3: weight prepack into B-fragment order ----------------
__global__ void k_prepack(const float* w32i, const uint16_t* w16i,
                          const float* w32h, const uint16_t* w16h, uint8_t* ws8) {
  int tid = blockIdx.x * 256 + threadIdx.x;  // 393216 threads
  int lane = tid & 63;
  int fragrow = (tid >> 6) % 96;
  int lg = tid / (96 * 64);  // 0..63
  int l = lg >> 5, g = lg & 31;
  int modeF = (int)*(const uint32_t*)(ws8 + WS_MODEF);
  int cg, kc;
  if (fragrow < 32)      { cg = 0; kc = fragrow; }
  else if (fragrow < 64) { cg = 1; kc = fragrow - 32; }
  else if (fragrow < 80) { cg = 2; kc = fragrow - 64; }
  else                   { cg = 3; kc = fragrow - 80; }
  int n = lane & 15, quad = lane >> 4;
  uint16_t* dst = (uint16_t*)(ws8 + WS_WPACK) + ((size_t)(lg * 96 + fragrow) * 64 + lane) * 8;
#pragma unroll
  for (int j = 0; j < 8; ++j) {
    int k = kc * 32 + quad * 8 + j;
    int col, kk;
    bool useWi;
    if (cg == 0)      { col = g * 16 + n;        useWi = (k < 512); kk = k & 511; }
    else if (cg == 1) { col = 512 + g * 16 + n;  useWi = (k < 512); kk = k & 511; }
    else if (cg == 2) { col = 1024 + g * 16 + n; useWi = true;      kk = k; }
    else              { col = 1024 + g * 16 + n; useWi = false;     kk = k; }
    size_t si = ((size_t)l * 512 + kk) * 1536 + col;
    uint16_t v;
    if (modeF) v = useWi ? w16i[si] : w16h[si];
    else       v = f2bf(useWi ? w32i[si] : w32h[si]);
    dst[j] = v;
  }
}

// ---------------- LDS tile layout (derived conflict-free, r4-proven) -------
// Tile = 16 rows x 512 bf16 (16 KB) as 1024 16-B chunks.
// chunk(f,row) = f*16 + (row ^ (f & 15)), f = kc*4 + quad (0..63), row 0..15.
__device__ __forceinline__ void st_tile(uint16_t* sb, int f, int row, v8s v) {
  *(v8s*)((uint8_t*)sb + (((f << 4) + (row ^ (f & 15))) << 4)) = v;
}
__device__ __forceinline__ v8s ld_tile(const uint16_t* sb, int f, int row) {
  return *(const v8s*)((const uint8_t*)sb + (((f << 4) + (row ^ (f & 15))) << 4));
}

// stage h tile (coherent ring reads, reset-zeroed). 512 thr x 2 chunks.
__device__ __forceinline__ void stage_hT(uint16_t* sb, const uint16_t* gp,
                                         const uint8_t* rrow, int tid) {
  const v8s vz = {0, 0, 0, 0, 0, 0, 0, 0};
  v8s v0 = ldc16(gp + (size_t)tid * 8);
  v8s v1 = ldc16(gp + (size_t)(tid + 512) * 8);
  int r0 = tid >> 6, f0 = tid & 63;
  int c1 = tid + 512, r1 = c1 >> 6, f1 = c1 & 63;
  st_tile(sb, f0, r0, rrow[r0] ? vz : v0);
  st_tile(sb, f1, r1, rrow[r1] ? vz : v1);
}
// stage bf16 x tile: coherent (ring0) or plain cached (ins) source
__device__ __forceinline__ void stage_xbf(uint16_t* sb, const uint16_t* g,
                                          int tid, bool coh) {
  v8s v0 = coh ? ldc16(g + (size_t)tid * 8) : ld_v8s(g + (size_t)tid * 8);
  int c1 = tid + 512;
  v8s v1 = coh ? ldc16(g + (size_t)c1 * 8) : ld_v8s(g + (size_t)c1 * 8);
  st_tile(sb, tid & 63, tid >> 6, v0);
  st_tile(sb, c1 & 63, c1 >> 6, v1);
}
// stage f32 x tile: plain cached loads + one-pass bf16 convert. 512 thr x 4.
__device__ __forceinline__ void stage_x32(uint16_t* sb, const float* g, int tid) {
#pragma unroll
  for (int i = 0; i < 4; ++i) {
    int cf = tid + 512 * i;           // 16-B f32 chunk (4 floats), 0..2047
    int row = cf >> 7, w8 = cf & 127; // 8-B bf16 chunk within row
    int f = w8 >> 1, half = w8 & 1;
    v4f x = *(const v4f*)(g + (size_t)cf * 4);
    u64 v = (u64)f2bf(x[0]) | ((u64)f2bf(x[1]) << 16)
          | ((u64)f2bf(x[2]) << 32) | ((u64)f2bf(x[3]) << 48);
    *(u64*)((uint8_t*)sb + (((f << 4) + (row ^ (f & 15))) << 4) + half * 8) = v;
  }
}

// ---------------- kernel 4: persistent pipelined GRU ----------------
// grid 128 = 2 layers x 4 row-tiles x 16 col-groups; 512 threads = 8 waves =
// 2 col-halves x 4 gate-roles.  Domain (l,rt) = 16 wgs, 32 publishers.
// Sync skeleton: IDENTICAL semantics to proven r4 (all cross-wg data and
// counters agent-scope at the MALL; publisher drains vmcnt then fetch_add;
// consumer tid-0 spins, barrier broadcasts).  New vs r4: 512-thr wgs halve
// coherent fan-in (3 MB/step) and poller count; dual-load poll = 1 RT/iter.
// role 0: r-gate (K=1024), role 1: z-gate (K=1024), role 2: inn (K=512, x),
// role 3: hn (K=512, h) + epilogue owner for its half (holds fp32 h master).
__launch_bounds__(512, 1)
__global__ void k_gru(const uint16_t* ins16, const float* ins32,
                      const float* bi32, const uint16_t* bi16,
                      const float* bhn32, const uint16_t* bhn16,
                      float* out32, uint16_t* out16, uint8_t* ws8) {
  const int tid = threadIdx.x;
  const int wave = tid >> 6, lane = tid & 63;
  const int half = wave >> 2, role = wave & 3;
  const int quad = lane >> 4, l16 = lane & 15;
  const int bid = (int)blockIdx.x;
  const int l = bid & 1;
  const int rt = (bid >> 1) & 3;
  const int gg = bid >> 3;              // 0..15

  uint32_t* abortf = (uint32_t*)(ws8 + WS_ABORT);
  uint32_t* ctrOwn = (uint32_t*)(ws8 + WS_CTR + (size_t)(l * 4 + rt) * 256);
  uint32_t* ctrOth = (uint32_t*)(ws8 + WS_CTR + (size_t)((1 - l) * 4 + rt) * 256);
  const uint8_t* rst = ws8 + WS_RESETS;
  uint16_t* ring0 = (uint16_t*)(ws8 + WS_RING0);
  uint16_t* ring1 = (uint16_t*)(ws8 + WS_RING1);
  uint16_t* ringS = l ? ring1 : ring0;
  const uint16_t* wsw = (const uint16_t*)(ws8 + WS_WPACK);
  const int modeF = (int)*(volatile const uint32_t*)(ws8 + WS_MODEF);

  // --- load this wave's B fragments into registers (persistent) ---
  const int slice = l * 32 + gg * 2 + half;         // 16-col slice 0..63
  const uint16_t* wbase = wsw + (size_t)slice * (96 * 64 * 8);
  const int nB = (role < 2) ? 32 : 16;
  const int fb = (role < 2) ? role * 32 : 64 + (role - 2) * 16;
  v8s Bv[32];
#pragma unroll
  for (int i = 0; i < 32; ++i)
    if (i < nB) Bv[i] = ld_v8s(wbase + ((size_t)(fb + i) * 64 + lane) * 8);

  // --- per-lane constants ---
  const int rowbase = rt * 16;
  const int cC = (gg * 2 + half) * 16 + l16;   // n-column owned in epilogue
  float bir, biz, bin_, bh;
  if (modeF) {
    const uint16_t* b16 = bi16 + l * 1536;
    bir = bf2f(b16[cC]); biz = bf2f(b16[512 + cC]); bin_ = bf2f(b16[1024 + cC]);
    bh = bf2f(bhn16[l * 512 + cC]);
  } else {
    const float* b32 = bi32 + l * 1536;
    bir = b32[cC]; biz = b32[512 + cC]; bin_ = b32[1024 + cC];
    bh = bhn32[l * 512 + cC];
  }

  __shared__ __align__(16) uint16_t hT[8192];          // h(t-1) tile, 16 KB
  __shared__ __align__(16) uint16_t xT[8192];          // x(t) tile, 16 KB
  __shared__ __align__(16) float eb[2][3][64][4];      // gate partials per half
  __shared__ __align__(16) uint16_t hstage[2][16][16]; // repack block per half

  float hm0 = 0.f, hm1 = 0.f, hm2 = 0.f, hm3 = 0.f;
  const int rEnd = l ? (T_ + 1) : T_;

  for (int r = 0; r < rEnd; ++r) {
    // ---- l0: prefetch x(r) from ins into LDS BEFORE the spin (off-path;
    //      xT reads of step r-1 all completed before barrier C) ----
    if (!l) {
      if (modeF) stage_xbf(xT, ins16 + ((size_t)r * 64 + rowbase) * 512, tid, false);
      else       stage_x32(xT, ins32 + ((size_t)r * 64 + rowbase) * 512, tid);
    }

    // ---- release: tid 0 spins, dual-load = one RT per poll iteration ----
    if (tid == 0) {
      const int nOwn = 32 * r;
      const int nOth = 32 * (l ? r : r - 6);   // l1: x ready; l0: ring throttle
      if (nOwn > 0 || nOth > 0) {
        int polls = 0;
        for (;;) {
          uint32_t a, b;
          asm volatile(
            "global_load_dword %0, %2, off sc0 sc1\n\t"
            "global_load_dword %1, %3, off sc0 sc1\n\t"
            "s_waitcnt vmcnt(0)"
            : "=&v"(a), "=&v"(b)
            : "v"(ctrOwn), "v"(ctrOth)
            : "memory");
          if ((int)a >= nOwn && (int)b >= nOth) break;
          if ((++polls & 3) == 0) __builtin_amdgcn_s_sleep(1);
          if ((polls & 255) == 0) {
            if (ld_u32_agent(abortf)) break;
            if (polls > (1 << 22)) {
              __hip_atomic_store(abortf, 1u, __ATOMIC_RELAXED, __HIP_MEMORY_SCOPE_AGENT);
              break;
            }
          }
        }
      }
    }
    __syncthreads();                    // (A) go signal for all waves
    asm volatile("" ::: "memory");      // no load hoisting above the spin

    const bool active = l ? (r > 0) : true;
    const int t = l ? (r - 1) : r;

    // ---- stage h (and l1's x) into LDS, once per wg ----
    if (active) {
      stage_hT(hT, ringS + (size_t)((t - 1) & 7) * (B_ * W_) + (size_t)rowbase * 512,
               rst + t * 64 + rowbase, tid);
      if (l)
        stage_xbf(xT, ring0 + (size_t)(t & 7) * (B_ * W_) + (size_t)rowbase * 512, tid, true);
    }
    __syncthreads();                    // (B) stage visible

    v4f a0 = {0.f, 0.f, 0.f, 0.f}, a1 = {0.f, 0.f, 0.f, 0.f};
    if (active) {
      if (role < 2) {
#pragma unroll
        for (int kc = 0; kc < 16; kc += 2) {  // x part, K 0..511
          v8s x0 = ld_tile(xT, kc * 4 + quad, l16);
          v8s x1 = ld_tile(xT, (kc + 1) * 4 + quad, l16);
          a0 = __builtin_amdgcn_mfma_f32_16x16x32_bf16(x0, Bv[kc], a0, 0, 0, 0);
          a1 = __builtin_amdgcn_mfma_f32_16x16x32_bf16(x1, Bv[kc + 1], a1, 0, 0, 0);
        }
#pragma unroll
        for (int kc = 0; kc < 16; kc += 2) {  // h part, K 512..1023
          v8s h0 = ld_tile(hT, kc * 4 + quad, l16);
          v8s h1 = ld_tile(hT, (kc + 1) * 4 + quad, l16);
          a0 = __builtin_amdgcn_mfma_f32_16x16x32_bf16(h0, Bv[16 + kc], a0, 0, 0, 0);
          a1 = __builtin_amdgcn_mfma_f32_16x16x32_bf16(h1, Bv[16 + kc + 1], a1, 0, 0, 0);
        }
      } else if (role == 2) {               // inn: x only
#pragma unroll
        for (int kc = 0; kc < 16; kc += 2) {
          v8s x0 = ld_tile(xT, kc * 4 + quad, l16);
          v8s x1 = ld_tile(xT, (kc + 1) * 4 + quad, l16);
          a0 = __builtin_amdgcn_mfma_f32_16x16x32_bf16(x0, Bv[kc], a0, 0, 0, 0);
          a1 = __builtin_amdgcn_mfma_f32_16x16x32_bf16(x1, Bv[kc + 1], a1, 0, 0, 0);
        }
      } else {                              // hn: h only
#pragma unroll
        for (int kc = 0; kc < 16; kc += 2) {
          v8s h0 = ld_tile(hT, kc * 4 + quad, l16);
          v8s h1 = ld_tile(hT, (kc + 1) * 4 + quad, l16);
          a0 = __builtin_amdgcn_mfma_f32_16x16x32_bf16(h0, Bv[kc], a0, 0, 0, 0);
          a1 = __builtin_amdgcn_mfma_f32_16x16x32_bf16(h1, Bv[kc + 1], a1, 0, 0, 0);
        }
      }
      if (role < 3) {
        v4f s = a0 + a1;
        *(v4f*)&eb[half][role][lane][0] = s;
      }
    }
    __syncthreads();                    // (C) gate partials visible

    // ---- role-3 tail (waves 3 and 7): epilogue, publish, drain, arrive.
    //      Other waves proceed straight to the next step's prefetch/spin. ----
    if (role == 3) {
      float hv0 = 0.f, hv1 = 0.f, hv2 = 0.f, hv3 = 0.f;
      if (active) {
        v4f accs = a0 + a1;
        v4f ra4 = *(const v4f*)&eb[half][0][lane][0];
        v4f za4 = *(const v4f*)&eb[half][1][lane][0];
        v4f ia4 = *(const v4f*)&eb[half][2][lane][0];
        float hv4[4];
        float hmv[4] = {hm0, hm1, hm2, hm3};
#pragma unroll
        for (int i = 0; i < 4; ++i) {
          float rg = 1.f / (1.f + __expf(-(ra4[i] + bir)));
          float zg = 1.f / (1.f + __expf(-(za4[i] + biz)));
          float narg = ia4[i] + bin_ + rg * (accs[i] + bh);
          float e2 = __expf(-2.f * fabsf(narg));
          float ng = (1.f - e2) / (1.f + e2);
          ng = (narg < 0.f) ? -ng : ng;
          int b = rowbase + quad * 4 + i;
          float hp_ = rst[t * 64 + b] ? 0.f : hmv[i];
          float hv = (1.f - zg) * ng + zg * hp_;
          hv4[i] = hv;
          hstage[half][quad * 4 + i][l16] = f2bf(hv);
        }
        hm0 = hv4[0]; hm1 = hv4[1]; hm2 = hv4[2]; hm3 = hv4[3];
        hv0 = hv4[0]; hv1 = hv4[1]; hv2 = hv4[2]; hv3 = hv4[3];
        // drain hstage LDS writes before cross-lane read-back (r3-proven)
        asm volatile("s_waitcnt lgkmcnt(0)" ::: "memory");
        __builtin_amdgcn_sched_barrier(0);
        int sr = lane >> 2, sc4 = lane & 3;
        u64 v = *(const u64*)&hstage[half][sr][sc4 * 4];
        u64* dst = (u64*)((uint8_t*)ringS
                          + (((size_t)(t & 7) * (B_ * W_)
                              + (size_t)(rowbase + sr) * 512
                              + (size_t)(gg * 2 + half) * 16) * 2 + (size_t)sc4 * 8));
        st_u64_agent(dst, v);
        // drain coherent h-stores before signalling arrival (r4-proven)
        asm volatile("s_waitcnt vmcnt(0)" ::: "memory");
      }
      // ---- arrive: one relaxed RMW at the MALL per publisher wave ----
      if (lane == 0)
        __hip_atomic_fetch_add(ctrOwn, 1u, __ATOMIC_RELAXED, __HIP_MEMORY_SCOPE_AGENT);

      if (active) {
        // deferred outputs (plain cached stores; off the signal path)
        float hv4[4] = {hv0, hv1, hv2, hv3};
#pragma unroll
        for (int i = 0; i < 4; ++i) {
          int b = rowbase + quad * 4 + i;
          if (l) {
            size_t off = (size_t)2 * B_ * W_ + ((size_t)t * 64 + b) * 512 + cC;
            if (modeF) out16[off] = f2bf(hv4[i]); else out32[off] = hv4[i];
          }
          if (t == T_ - 1) {
            size_t off = (size_t)l * (B_ * W_) + (size_t)b * 512 + cC;
            if (modeF) out16[off] = f2bf(hv4[i]); else out32[off] = hv4[i];
          }
        }
      }
    }
  }
}

// ---------------- launcher ----------------
extern "C" void kernel_launch(void* const* d_in, const int* in_sizes, int n_in,
                              void* d_out, int out_size, void* d_ws, size_t ws_size,
                              hipStream_t stream) {
  (void)in_sizes; (void)n_in; (void)out_size;
  if (ws_size < (size_t)WS_NEEDED) return;  // visible failure rather than corruption

  const void* ins = d_in[0];
  const void* rst = d_in[1];
  const void* Wi  = d_in[2];
  const void* bi  = d_in[3];
  const void* Wh  = d_in[4];
  const void* bhn = d_in[5];
  uint8_t* ws8 = (uint8_t*)d_ws;

  hipMemsetAsync(d_ws, 0, 8192, stream);  // modes + abort + domain counters
  hipLaunchKernelGGL(k_detect, dim3(64), dim3(256), 0, stream,
                     (const uint32_t*)rst, (const uint32_t*)ins,
                     (uint32_t*)(ws8 + WS_FLAGS), (uint32_t*)(ws8 + WS_VOTES));
  hipLaunchKernelGGL(k_init, dim3(1024), dim3(256), 0, stream,
                     (const uint8_t*)rst, ws8);
  hipLaunchKernelGGL(k_prepack, dim3(1536), dim3(256), 0, stream,
                     (const float*)Wi, (const uint16_t*)Wi,
                     (const float*)Wh, (const uint16_t*)Wh, ws8);
  hipLaunchKernelGGL(k_gru, dim3(128), dim3(512), 0, stream,
                     (const uint16_t*)ins, (const float*)ins,
                     (const float*)bi, (const uint16_t*)bi,
                     (const float*)bhn, (const uint16_t*)bhn,
                     (float*)d_out, (uint16_t*)d_out, ws8);
}